// Round 2
// baseline (923.851 us; speedup 1.0000x reference)
//
#include <hip/hip_runtime.h>
#include <math.h>

// NetVLAD fused: scores GEMM + softmax -> p (ws), agg GEMM + center-subtract,
// double L2 normalize. fp32 throughout (correctness-first baseline).
// B=32, D=512, N=2048, K=64.

namespace {
constexpr int Bv = 32;
constexpr int Dv = 512;
constexpr int Nv = 2048;
constexpr int Kv = 64;
constexpr float EPSv = 1e-12f;
}

__global__ __launch_bounds__(256) void k_zero(float* __restrict__ s, int n) {
  int i = blockIdx.x * 256 + threadIdx.x;
  if (i < n) s[i] = 0.f;
}

// ---------------------------------------------------------------------------
// K1: scores[b,k,n] = sum_d W[k,d] * x[b,d,n]; softmax over k; write p;
//     accumulate s_sum[b,k] = sum_n p[b,k,n] via wave-reduce + atomicAdd.
// One thread per (b, n). W reads are wave-uniform -> scalar loads (s_load),
// so the inner loop is v_fmac with an SGPR operand: 1 instr / FMA.
// ---------------------------------------------------------------------------
__global__ __launch_bounds__(256) void k_scores(const float* __restrict__ x,
                                                const float* __restrict__ Wt,
                                                float* __restrict__ p,
                                                float* __restrict__ s_sum) {
  const int b = blockIdx.y;
  const int n = blockIdx.x * 256 + threadIdx.x;
  const float* xb = x + (size_t)b * Dv * Nv + n;  // x[b, d, n] = xb[d*Nv]

  float sc[Kv];
#pragma unroll
  for (int k = 0; k < Kv; ++k) sc[k] = 0.f;

  // Register double-buffered chunks of 16 d's. Named buffers (no runtime
  // array indexing -> stays in VGPRs).
  float xva[16], xvb[16];

#define LOADC(dst, c)                                         \
  _Pragma("unroll") for (int j = 0; j < 16; ++j) {            \
    dst[j] = xb[(size_t)((c)*16 + j) * Nv];                   \
  }

#define COMPC(src, c)                                         \
  _Pragma("unroll") for (int k = 0; k < Kv; ++k) {            \
    _Pragma("unroll") for (int j = 0; j < 16; ++j) {          \
      sc[k] = fmaf(Wt[k * Dv + (c)*16 + j], src[j], sc[k]);   \
    }                                                         \
  }

  LOADC(xva, 0);
  for (int c = 0; c < Dv / 16; c += 2) {
    LOADC(xvb, c + 1);
    COMPC(xva, c);
    if (c + 2 < Dv / 16) {
      LOADC(xva, c + 2);
    }
    COMPC(xvb, c + 1);
  }
#undef LOADC
#undef COMPC

  // softmax over k (in registers)
  float m = sc[0];
#pragma unroll
  for (int k = 1; k < Kv; ++k) m = fmaxf(m, sc[k]);
  float s = 0.f;
#pragma unroll
  for (int k = 0; k < Kv; ++k) {
    sc[k] = __expf(sc[k] - m);
    s += sc[k];
  }
  const float rs = 1.f / s;

  float* pb = p + (size_t)b * Kv * Nv + n;
#pragma unroll
  for (int k = 0; k < Kv; ++k) {
    sc[k] *= rs;
    pb[(size_t)k * Nv] = sc[k];  // coalesced across lanes (consecutive n)
  }

  // s_sum[b,k] += sum over this wave's 64 n's, one atomic per wave per k
  const int lane = threadIdx.x & 63;
#pragma unroll
  for (int k = 0; k < Kv; ++k) {
    float v = sc[k];
#pragma unroll
    for (int off = 32; off > 0; off >>= 1) v += __shfl_xor(v, off);
    if (lane == 0) atomicAdd(&s_sum[b * Kv + k], v);
  }
}

// ---------------------------------------------------------------------------
// K2: agg[b,d,k] = sum_n x[b,d,n] * p[b,k,n]; out = agg - centers[d,k]*s_sum.
// Block: 64d x 64k tile, full N reduction. LDS double-buffered chunks of
// 32 n, stored transposed [n][d] / [n][k] with stride 68 (16B-aligned rows,
// conflict-free-enough) so compute uses ds_read_b128.
// ---------------------------------------------------------------------------
__global__ __launch_bounds__(256) void k_agg(const float* __restrict__ x,
                                             const float* __restrict__ p,
                                             const float* __restrict__ centers,
                                             const float* __restrict__ s_sum,
                                             float* __restrict__ out) {
  const int b = blockIdx.y;
  const int d0 = blockIdx.x * 64;

  __shared__ __align__(16) float xs[2][32][68];  // [buf][n][d]
  __shared__ __align__(16) float ps[2][32][68];  // [buf][n][k]

  const int tx = threadIdx.x & 15;   // k-group: 4 k's
  const int ty = threadIdx.x >> 4;   // d-group: 4 d's
  const int lnn = threadIdx.x & 31;  // load: n within chunk
  const int lr = threadIdx.x >> 5;   // load: row base (0..7)

  const float* xb = x + (size_t)b * Dv * Nv;
  const float* pb = p + (size_t)b * Kv * Nv;

  float acc[4][4];
#pragma unroll
  for (int i = 0; i < 4; ++i)
#pragma unroll
    for (int j = 0; j < 4; ++j) acc[i][j] = 0.f;

#define LOADT(buf, n0)                                                   \
  do {                                                                   \
    _Pragma("unroll") for (int r = 0; r < 8; ++r) {                      \
      const int row = lr + r * 8;                                        \
      xs[buf][lnn][row] = xb[(size_t)(d0 + row) * Nv + (n0) + lnn];      \
      ps[buf][lnn][row] = pb[(size_t)row * Nv + (n0) + lnn];             \
    }                                                                    \
  } while (0)

#define COMPT(buf)                                                       \
  do {                                                                   \
    _Pragma("unroll") for (int nn = 0; nn < 32; ++nn) {                  \
      const float4 xv = *(const float4*)&xs[buf][nn][ty * 4];            \
      const float4 pv = *(const float4*)&ps[buf][nn][tx * 4];            \
      const float xr[4] = {xv.x, xv.y, xv.z, xv.w};                      \
      const float pr[4] = {pv.x, pv.y, pv.z, pv.w};                      \
      _Pragma("unroll") for (int i = 0; i < 4; ++i) {                    \
        _Pragma("unroll") for (int j = 0; j < 4; ++j) {                  \
          acc[i][j] = fmaf(xr[i], pr[j], acc[i][j]);                     \
        }                                                                \
      }                                                                  \
    }                                                                    \
  } while (0)

  LOADT(0, 0);
  __syncthreads();
  for (int c = 0; c < Nv / 32; ++c) {
    const int cur = c & 1;
    if (c + 1 < Nv / 32) LOADT(cur ^ 1, (c + 1) * 32);
    COMPT(cur);
    __syncthreads();
  }
#undef LOADT
#undef COMPT

  // Epilogue: subtract centers*s_sum, store unnormalized desc to out.
  const int k0 = tx * 4;
  const int dd0 = ty * 4;
  float ssv[4];
#pragma unroll
  for (int j = 0; j < 4; ++j) ssv[j] = s_sum[b * Kv + k0 + j];

#pragma unroll
  for (int i = 0; i < 4; ++i) {
    const int d = d0 + dd0 + i;
    float4 o;
    o.x = acc[i][0] - centers[d * Kv + k0 + 0] * ssv[0];
    o.y = acc[i][1] - centers[d * Kv + k0 + 1] * ssv[1];
    o.z = acc[i][2] - centers[d * Kv + k0 + 2] * ssv[2];
    o.w = acc[i][3] - centers[d * Kv + k0 + 3] * ssv[3];
    *(float4*)&out[((size_t)b * Dv + d) * Kv + k0] = o;
  }
}

// ---------------------------------------------------------------------------
// K3: per batch: L2-normalize each k-column over D, then L2-normalize the
// whole [D*K] row. Second norm computed analytically from post-intranorm
// column norms (t * rn^2 per column).
// ---------------------------------------------------------------------------
__global__ __launch_bounds__(256) void k_norm(float* __restrict__ out) {
  const int b = blockIdx.x;
  float* ob = out + (size_t)b * (Dv * Kv);
  const int k = threadIdx.x & 63;
  const int dq = threadIdx.x >> 6;  // d-quarter, 128 d's each

  __shared__ float red[4][64];
  __shared__ float rnorm[64];
  __shared__ float rtot_s;

  float ssq = 0.f;
  for (int d = dq * 128; d < dq * 128 + 128; ++d) {
    const float v = ob[d * Kv + k];  // coalesced: consecutive k across lanes
    ssq = fmaf(v, v, ssq);
  }
  red[dq][k] = ssq;
  __syncthreads();

  if (threadIdx.x < 64) {
    const int kk = threadIdx.x;
    const float t = red[0][kk] + red[1][kk] + red[2][kk] + red[3][kk];
    const float rn = 1.f / fmaxf(sqrtf(t), EPSv);
    rnorm[kk] = rn;
    red[0][kk] = t * rn * rn;  // column sumsq after intranorm
  }
  __syncthreads();

  if (threadIdx.x == 0) {
    float t = 0.f;
    for (int kk = 0; kk < 64; ++kk) t += red[0][kk];
    rtot_s = 1.f / fmaxf(sqrtf(t), EPSv);
  }
  __syncthreads();

  const float scale = rnorm[k] * rtot_s;
  for (int d = dq * 128; d < dq * 128 + 128; ++d) {
    ob[d * Kv + k] *= scale;
  }
}

// ---------------------------------------------------------------------------
extern "C" void kernel_launch(void* const* d_in, const int* in_sizes, int n_in,
                              void* d_out, int out_size, void* d_ws, size_t ws_size,
                              hipStream_t stream) {
  (void)in_sizes; (void)n_in; (void)out_size; (void)ws_size;
  const float* x = (const float*)d_in[0];        // [B, D, N]
  const float* W = (const float*)d_in[1];        // [K, D]
  const float* centers = (const float*)d_in[2];  // [D, K]
  float* out = (float*)d_out;                    // [B, D*K]

  // ws layout: p [B*K*N] fp32 (16.78 MB), then s_sum [B*K]
  float* p = (float*)d_ws;
  float* s_sum = p + (size_t)Bv * Kv * Nv;

  k_zero<<<dim3((Bv * Kv + 255) / 256), 256, 0, stream>>>(s_sum, Bv * Kv);
  k_scores<<<dim3(Nv / 256, Bv), 256, 0, stream>>>(x, W, p, s_sum);
  k_agg<<<dim3(Dv / 64, Bv), 256, 0, stream>>>(x, p, centers, s_sum, out);
  k_norm<<<Bv, 256, 0, stream>>>(out);
}

// Round 3
// 428.196 us; speedup vs baseline: 2.1575x; 2.1575x over previous
//
#include <hip/hip_runtime.h>
#include <math.h>

// NetVLAD fused, fp32. R3: occupancy restructure.
// R2 post-mortem: 1 wave/SIMD + 64 accumulators/thread -> 678us k_scores at
// VALUBusy 15%. Fix: k-split across waves (16 acc/thread), 4x more blocks.
// B=32, D=512, N=2048, K=64.

namespace {
constexpr int Bv = 32;
constexpr int Dv = 512;
constexpr int Nv = 2048;
constexpr int Kv = 64;
constexpr int NSPLIT = 4;  // k_agg n-range split (512 n each)
constexpr float EPSv = 1e-12f;
}

// Zero out (atomic accumulator) + s_sum/colsq. grid 4096x256 covers 1M.
__global__ __launch_bounds__(256) void k_zero(float* __restrict__ out,
                                              float* __restrict__ aux) {
  int i = blockIdx.x * 256 + threadIdx.x;
  if (i < Bv * Dv * Kv) out[i] = 0.f;
  if (i < 2 * Bv * Kv) aux[i] = 0.f;
}

// ---------------------------------------------------------------------------
// K1: scores + softmax -> p, s_sum. Block: 64 n x all 64 k; wave w owns
// k in [16w, 16w+16). x chunk [16 d][64 n] LDS double-buffered (8KB).
// W via readfirstlane-forced SGPR indexing -> s_load, v_fmac s-operand.
// Grid (N/64, B) = 1024 blocks -> 4 waves/SIMD.
// ---------------------------------------------------------------------------
__global__ __launch_bounds__(256) void k_scores(const float* __restrict__ x,
                                                const float* __restrict__ Wt,
                                                float* __restrict__ p,
                                                float* __restrict__ s_sum) {
  const int b = blockIdx.y;
  const int nl = threadIdx.x & 63;
  const int tw = threadIdx.x >> 6;  // wave id (vector form, for staging)
  const int wv = __builtin_amdgcn_readfirstlane(tw);  // scalar wave id
  const int n = blockIdx.x * 64 + nl;

  const float* xb = x + (size_t)b * Dv * Nv + n;
  const float* Wk = Wt + (size_t)wv * 16 * Dv;  // this wave's 16 k-rows

  __shared__ float xs[2][16][64];
  __shared__ float redm[4][64];
  __shared__ float reds[4][64];

  float sc[16];
#pragma unroll
  for (int kk = 0; kk < 16; ++kk) sc[kk] = 0.f;

#define STAGE(buf, c)                                              \
  _Pragma("unroll") for (int i = 0; i < 4; ++i) {                  \
    const int row = tw * 4 + i;                                    \
    xs[buf][row][nl] = xb[(size_t)((c) * 16 + row) * Nv];          \
  }

  STAGE(0, 0);
  __syncthreads();
  for (int c = 0; c < Dv / 16; ++c) {
    const int cur = c & 1;
    if (c + 1 < Dv / 16) { STAGE(cur ^ 1, c + 1); }
    const int cd = c * 16;
#pragma unroll
    for (int j = 0; j < 16; ++j) {
      const float xj = xs[cur][j][nl];
#pragma unroll
      for (int kk = 0; kk < 16; ++kk) {
        sc[kk] = fmaf(Wk[kk * Dv + cd + j], xj, sc[kk]);
      }
    }
    __syncthreads();
  }
#undef STAGE

  // --- softmax over all 64 k (cross-wave via LDS) ---
  float lm = sc[0];
#pragma unroll
  for (int kk = 1; kk < 16; ++kk) lm = fmaxf(lm, sc[kk]);
  redm[tw][nl] = lm;
  __syncthreads();
  const float m = fmaxf(fmaxf(redm[0][nl], redm[1][nl]),
                        fmaxf(redm[2][nl], redm[3][nl]));

  float ls = 0.f;
#pragma unroll
  for (int kk = 0; kk < 16; ++kk) {
    sc[kk] = __expf(sc[kk] - m);
    ls += sc[kk];
  }
  reds[tw][nl] = ls;
  __syncthreads();
  const float s = reds[0][nl] + reds[1][nl] + reds[2][nl] + reds[3][nl];
  const float rs = 1.f / s;

  float* pb = p + (size_t)b * Kv * Nv + n;
  const int lane = threadIdx.x & 63;
#pragma unroll
  for (int kk = 0; kk < 16; ++kk) {
    const float val = sc[kk] * rs;
    pb[(size_t)(wv * 16 + kk) * Nv] = val;  // coalesced (consecutive n)
    float v = val;
#pragma unroll
    for (int off = 32; off > 0; off >>= 1) v += __shfl_xor(v, off);
    if (lane == 0) atomicAdd(&s_sum[b * Kv + wv * 16 + kk], v);
  }
}

// ---------------------------------------------------------------------------
// K2: partial agg[b,d,k] over an n-range of 512, atomicAdd into out.
// Tile 128d x 64k, thread-tile 8x4 (256 thr). LDS chunks of 32 n,
// [n][d] stride 132 / [n][k] stride 68 (16B-aligned rows; x-reads broadcast
// across the 16 tx-lanes -> near-free; writes 4-way = 1.58x, acceptable).
// Grid (4, NSPLIT, 32) = 512 blocks.
// ---------------------------------------------------------------------------
__global__ __launch_bounds__(256) void k_agg(const float* __restrict__ x,
                                             const float* __restrict__ p,
                                             float* __restrict__ out) {
  const int dblk = blockIdx.x;      // 0..3 -> d base
  const int ns = blockIdx.y;        // 0..NSPLIT-1
  const int b = blockIdx.z;
  const int d_base = dblk * 128;
  const int n_base = ns * (Nv / NSPLIT);

  __shared__ __align__(16) float xs[2][32][132];
  __shared__ __align__(16) float ps[2][32][68];

  const int tx = threadIdx.x & 15;   // k: 4 per thread
  const int ty = threadIdx.x >> 4;   // d: 8 per thread
  const int lnn = threadIdx.x & 31;  // staging n
  const int lr = threadIdx.x >> 5;   // staging row base 0..7

  const float* xb = x + (size_t)b * Dv * Nv;
  const float* pb = p + (size_t)b * Kv * Nv;

  float acc[8][4];
#pragma unroll
  for (int i = 0; i < 8; ++i)
#pragma unroll
    for (int j = 0; j < 4; ++j) acc[i][j] = 0.f;

#define LOADT(buf, n0)                                                  \
  do {                                                                  \
    _Pragma("unroll") for (int r = 0; r < 16; ++r) {                    \
      const int row = lr + r * 8;                                       \
      xs[buf][lnn][row] = xb[(size_t)(d_base + row) * Nv + (n0) + lnn]; \
    }                                                                   \
    _Pragma("unroll") for (int r = 0; r < 8; ++r) {                     \
      const int row = lr + r * 8;                                       \
      ps[buf][lnn][row] = pb[(size_t)row * Nv + (n0) + lnn];            \
    }                                                                   \
  } while (0)

#define COMPT(buf)                                                      \
  do {                                                                  \
    _Pragma("unroll") for (int nn = 0; nn < 32; ++nn) {                 \
      const float4 xa = *(const float4*)&xs[buf][nn][ty * 8];           \
      const float4 xc = *(const float4*)&xs[buf][nn][ty * 8 + 4];       \
      const float4 pv = *(const float4*)&ps[buf][nn][tx * 4];           \
      const float xr[8] = {xa.x, xa.y, xa.z, xa.w, xc.x, xc.y, xc.z, xc.w}; \
      const float pr[4] = {pv.x, pv.y, pv.z, pv.w};                     \
      _Pragma("unroll") for (int i = 0; i < 8; ++i) {                   \
        _Pragma("unroll") for (int j = 0; j < 4; ++j) {                 \
          acc[i][j] = fmaf(xr[i], pr[j], acc[i][j]);                    \
        }                                                               \
      }                                                                 \
    }                                                                   \
  } while (0)

  LOADT(0, n_base);
  __syncthreads();
  const int NCH = (Nv / NSPLIT) / 32;  // 16 chunks
  for (int c = 0; c < NCH; ++c) {
    const int cur = c & 1;
    if (c + 1 < NCH) LOADT(cur ^ 1, n_base + (c + 1) * 32);
    COMPT(cur);
    __syncthreads();
  }
#undef LOADT
#undef COMPT

  // Partial-sum into out (zeroed by k_zero).
#pragma unroll
  for (int i = 0; i < 8; ++i) {
    const int d = d_base + ty * 8 + i;
#pragma unroll
    for (int j = 0; j < 4; ++j) {
      const int k = tx * 4 + j;
      atomicAdd(&out[((size_t)b * Dv + d) * Kv + k], acc[i][j]);
    }
  }
}

// ---------------------------------------------------------------------------
// K3a: column sumsq of desc = out - centers*s_sum -> colsq atomics.
// Grid (8, 32): 64 d-rows per block.
// ---------------------------------------------------------------------------
__global__ __launch_bounds__(256) void k_norm1(const float* __restrict__ out,
                                               const float* __restrict__ centers,
                                               const float* __restrict__ s_sum,
                                               float* __restrict__ colsq) {
  const int b = blockIdx.y;
  const int d0 = blockIdx.x * 64;
  const int k = threadIdx.x & 63;
  const int dq = threadIdx.x >> 6;

  __shared__ float red[4][64];

  const float sv = s_sum[b * Kv + k];
  float ssq = 0.f;
#pragma unroll
  for (int i = 0; i < 16; ++i) {
    const int d = d0 + dq * 16 + i;
    const float a = out[((size_t)b * Dv + d) * Kv + k];
    const float v = fmaf(-centers[d * Kv + k], sv, a);
    ssq = fmaf(v, v, ssq);
  }
  red[dq][k] = ssq;
  __syncthreads();
  if (threadIdx.x < 64) {
    const int kk = threadIdx.x;
    atomicAdd(&colsq[b * Kv + kk],
              red[0][kk] + red[1][kk] + red[2][kk] + red[3][kk]);
  }
}

// ---------------------------------------------------------------------------
// K3b: final scale: out = (out - centers*s_sum) * rn[k] * rtot.
// rtot from analytic identity sum_k colsq_k * rn_k^2. Grid (8, 32).
// ---------------------------------------------------------------------------
__global__ __launch_bounds__(256) void k_norm2(float* __restrict__ out,
                                               const float* __restrict__ centers,
                                               const float* __restrict__ s_sum,
                                               const float* __restrict__ colsq) {
  const int b = blockIdx.y;
  const int d0 = blockIdx.x * 64;
  const int k = threadIdx.x & 63;
  const int dq = threadIdx.x >> 6;

  __shared__ float rns[64];
  __shared__ float red2[64];
  __shared__ float rtot_s;

  if (threadIdx.x < 64) {
    const float t = colsq[b * Kv + threadIdx.x];
    const float rn = 1.f / fmaxf(sqrtf(t), EPSv);
    rns[threadIdx.x] = rn;
    red2[threadIdx.x] = t * rn * rn;
  }
  __syncthreads();
  if (threadIdx.x == 0) {
    float t = 0.f;
#pragma unroll
    for (int kk = 0; kk < 64; ++kk) t += red2[kk];
    rtot_s = 1.f / fmaxf(sqrtf(t), EPSv);
  }
  __syncthreads();

  const float scale = rns[k] * rtot_s;
  const float sv = s_sum[b * Kv + k];
#pragma unroll
  for (int i = 0; i < 16; ++i) {
    const int d = d0 + dq * 16 + i;
    const size_t idx = ((size_t)b * Dv + d) * Kv + k;
    const float v = fmaf(-centers[d * Kv + k], sv, out[idx]);
    out[idx] = v * scale;
  }
}

// ---------------------------------------------------------------------------
extern "C" void kernel_launch(void* const* d_in, const int* in_sizes, int n_in,
                              void* d_out, int out_size, void* d_ws, size_t ws_size,
                              hipStream_t stream) {
  (void)in_sizes; (void)n_in; (void)out_size; (void)ws_size;
  const float* x = (const float*)d_in[0];        // [B, D, N]
  const float* W = (const float*)d_in[1];        // [K, D]
  const float* centers = (const float*)d_in[2];  // [D, K]
  float* out = (float*)d_out;                    // [B, D*K]

  // ws: p [B*K*N] fp32, s_sum [B*K], colsq [B*K]
  float* p = (float*)d_ws;
  float* s_sum = p + (size_t)Bv * Kv * Nv;
  float* colsq = s_sum + Bv * Kv;

  k_zero<<<dim3((Bv * Dv * Kv + 255) / 256), 256, 0, stream>>>(out, s_sum);
  k_scores<<<dim3(Nv / 64, Bv), 256, 0, stream>>>(x, W, p, s_sum);
  k_agg<<<dim3(Dv / 128, NSPLIT, Bv), 256, 0, stream>>>(x, p, out);
  k_norm1<<<dim3(Dv / 64, Bv), 256, 0, stream>>>(out, centers, s_sum, colsq);
  k_norm2<<<dim3(Dv / 64, Bv), 256, 0, stream>>>(out, centers, s_sum, colsq);
}

// Round 4
// 317.305 us; speedup vs baseline: 2.9116x; 1.3495x over previous
//
#include <hip/hip_runtime.h>
#include <math.h>

// NetVLAD fused. R4: both GEMMs on MFMA (16x16x32 bf16) with split-bf16
// (hi+lo truncation, 3-pass) for ~fp32 accuracy. T14 async staging.
// B=32, D=512, N=2048, K=64.

typedef __attribute__((ext_vector_type(8))) short bf16x8;
typedef __attribute__((ext_vector_type(4))) float f32x4;

namespace {
constexpr int Bv = 32;
constexpr int Dv = 512;
constexpr int Nv = 2048;
constexpr int Kv = 64;
constexpr float EPSv = 1e-12f;
}

union Frag {
  uint4 q;
  bf16x8 v;
};

// truncation split: hi = top16(v) (exact bf16), lo = bf16(v - hi) (v-hi exact in f32)
__device__ __forceinline__ unsigned pack2bf(float a, float b) {
  return (__float_as_uint(a) >> 16) | (__float_as_uint(b) & 0xFFFF0000u);
}
__device__ __forceinline__ float hi_f32(float a) {
  return __uint_as_float(__float_as_uint(a) & 0xFFFF0000u);
}
__device__ __forceinline__ void split8(const float4& a, const float4& b,
                                       uint4& h, uint4& l) {
  const float f[8] = {a.x, a.y, a.z, a.w, b.x, b.y, b.z, b.w};
  unsigned* hp = (unsigned*)&h;
  unsigned* lp = (unsigned*)&l;
#pragma unroll
  for (int j = 0; j < 4; ++j) {
    const float e = f[2 * j], o = f[2 * j + 1];
    hp[j] = pack2bf(e, o);
    lp[j] = pack2bf(e - hi_f32(e), o - hi_f32(o));
  }
}

// ---------------------------------------------------------------------------
// Prep: zero out (atomic target) + s_sum/colsq; convert W -> Whi/Wlo bf16.
// ---------------------------------------------------------------------------
__global__ __launch_bounds__(256) void k_prep(const float* __restrict__ W,
                                              float* __restrict__ out,
                                              float* __restrict__ aux,
                                              unsigned short* __restrict__ Whi,
                                              unsigned short* __restrict__ Wlo) {
  const int i = blockIdx.x * 256 + threadIdx.x;
  if (i < Bv * Dv * Kv) out[i] = 0.f;
  if (i < Kv * Dv) {
    const float w = W[i];
    Whi[i] = (unsigned short)(__float_as_uint(w) >> 16);
    Wlo[i] = (unsigned short)(__float_as_uint(w - hi_f32(w)) >> 16);
  }
  if (i < 2 * Bv * Kv) aux[i] = 0.f;
}

// ---------------------------------------------------------------------------
// K1: scores = W·x[b] (M=64 k, K-dim=512 d, N=2048 n) via MFMA, softmax over
// k in-register, p (fp32, [k][n]) via LDS transpose, s_sum atomics.
// Block: 64k x 64n, 4 waves = 4 n-strips of 16. Grid (32, 32).
// LDS: W tiles bf16 hi/lo dbuf (20KB) + x tile fp32 dbuf (17.4KB, aliased
// as p-transpose tile after the K-loop). 37.9KB -> 4 blocks/CU.
// ---------------------------------------------------------------------------
__global__ __launch_bounds__(256) void k_scores(const float* __restrict__ x,
                                                const unsigned short* __restrict__ Whi,
                                                const unsigned short* __restrict__ Wlo,
                                                float* __restrict__ p,
                                                float* __restrict__ s_sum) {
  const int b = blockIdx.y;
  const int n0 = blockIdx.x * 64;
  const int tid = threadIdx.x;
  const int lane = tid & 63;
  const int wv = tid >> 6;
  const int r = lane & 15;
  const int g = lane >> 4;

  __shared__ __align__(16) unsigned short wlds[2][2][64][40];  // [buf][hi/lo][k][d] 80B rows
  __shared__ __align__(16) float xlds[2][32][68];              // [buf][d][n] (4352 floats)
  float* plds = &xlds[0][0][0];  // aliased after K-loop: [64][68] = 4352 floats

  const float* xb = x + (size_t)b * Dv * Nv;

  f32x4 acc[4];
#pragma unroll
  for (int mb = 0; mb < 4; ++mb) acc[mb] = (f32x4){0.f, 0.f, 0.f, 0.f};

  // staging assignments
  const int wk = tid >> 2;   // W row 0..63
  const int wdg = tid & 3;   // W 16B group
  const int xd = tid >> 3;   // x d-row 0..31
  const int xng = tid & 7;   // x n-group

  uint4 rwh, rwl;
  float4 rxa, rxb;

#define GLOAD(s)                                                          \
  do {                                                                    \
    rwh = *(const uint4*)&Whi[wk * Dv + (s) * 32 + wdg * 8];              \
    rwl = *(const uint4*)&Wlo[wk * Dv + (s) * 32 + wdg * 8];              \
    const float* src = &xb[(size_t)((s) * 32 + xd) * Nv + n0 + xng * 8];  \
    rxa = *(const float4*)src;                                            \
    rxb = *(const float4*)(src + 4);                                      \
  } while (0)

#define LWRITE(buf)                                   \
  do {                                                \
    *(uint4*)&wlds[buf][0][wk][wdg * 8] = rwh;        \
    *(uint4*)&wlds[buf][1][wk][wdg * 8] = rwl;        \
    *(float4*)&xlds[buf][xd][xng * 8] = rxa;          \
    *(float4*)&xlds[buf][xd][xng * 8 + 4] = rxb;      \
  } while (0)

#define COMPUTE(buf)                                                          \
  do {                                                                        \
    float xf[8];                                                              \
    _Pragma("unroll") for (int j = 0; j < 8; ++j)                             \
        xf[j] = xlds[buf][g * 8 + j][wv * 16 + r];                            \
    Frag bh, bl;                                                              \
    _Pragma("unroll") for (int j = 0; j < 4; ++j) {                           \
      const float e = xf[2 * j], o = xf[2 * j + 1];                           \
      ((unsigned*)&bh.q)[j] = pack2bf(e, o);                                  \
      ((unsigned*)&bl.q)[j] = pack2bf(e - hi_f32(e), o - hi_f32(o));          \
    }                                                                         \
    _Pragma("unroll") for (int mb = 0; mb < 4; ++mb) {                        \
      Frag ah, al;                                                            \
      ah.q = *(const uint4*)&wlds[buf][0][mb * 16 + r][g * 8];                \
      al.q = *(const uint4*)&wlds[buf][1][mb * 16 + r][g * 8];                \
      acc[mb] = __builtin_amdgcn_mfma_f32_16x16x32_bf16(ah.v, bh.v, acc[mb], 0, 0, 0); \
      acc[mb] = __builtin_amdgcn_mfma_f32_16x16x32_bf16(ah.v, bl.v, acc[mb], 0, 0, 0); \
      acc[mb] = __builtin_amdgcn_mfma_f32_16x16x32_bf16(al.v, bh.v, acc[mb], 0, 0, 0); \
    }                                                                         \
  } while (0)

  GLOAD(0);
  LWRITE(0);
  __syncthreads();
  for (int s = 0; s < Dv / 32; ++s) {
    const int cur = s & 1;
    if (s + 1 < Dv / 32) GLOAD(s + 1);
    COMPUTE(cur);
    if (s + 1 < Dv / 32) LWRITE(cur ^ 1);
    __syncthreads();
  }
#undef GLOAD
#undef LWRITE
#undef COMPUTE

  // ---- softmax over k (lane holds 16 k's for one n; cross-lane over l>>4) ----
  float v[16];
#pragma unroll
  for (int mb = 0; mb < 4; ++mb)
#pragma unroll
    for (int q = 0; q < 4; ++q) v[mb * 4 + q] = acc[mb][q];

  float m = v[0];
#pragma unroll
  for (int i = 1; i < 16; ++i) m = fmaxf(m, v[i]);
  m = fmaxf(m, __shfl_xor(m, 16));
  m = fmaxf(m, __shfl_xor(m, 32));

  float sm = 0.f;
#pragma unroll
  for (int i = 0; i < 16; ++i) {
    v[i] = __expf(v[i] - m);
    sm += v[i];
  }
  sm += __shfl_xor(sm, 16);
  sm += __shfl_xor(sm, 32);
  const float rs = 1.f / sm;

  // transpose through LDS: plds[k][n-local], stride 68 (2-way conflicts max)
  const int nl = wv * 16 + r;
#pragma unroll
  for (int mb = 0; mb < 4; ++mb)
#pragma unroll
    for (int q = 0; q < 4; ++q)
      plds[(mb * 16 + g * 4 + q) * 68 + nl] = v[mb * 4 + q] * rs;
  __syncthreads();

  // coalesced store of p[b][k][n0..n0+64) + s_sum partial
  const int pk = tid >> 2;
  const int png = tid & 3;
  const float4 p0 = *(const float4*)&plds[pk * 68 + png * 16];
  const float4 p1 = *(const float4*)&plds[pk * 68 + png * 16 + 4];
  const float4 p2 = *(const float4*)&plds[pk * 68 + png * 16 + 8];
  const float4 p3 = *(const float4*)&plds[pk * 68 + png * 16 + 12];
  const float part = (p0.x + p0.y + p0.z + p0.w) + (p1.x + p1.y + p1.z + p1.w) +
                     (p2.x + p2.y + p2.z + p2.w) + (p3.x + p3.y + p3.z + p3.w);
  atomicAdd(&s_sum[b * Kv + pk], part);
  float* dst = &p[((size_t)b * Kv + pk) * Nv + n0 + png * 16];
  *(float4*)dst = p0;
  *(float4*)(dst + 4) = p1;
  *(float4*)(dst + 8) = p2;
  *(float4*)(dst + 12) = p3;
}

// ---------------------------------------------------------------------------
// K2: agg[b,d,k] = sum_n x[b,d,n]*p[b,k,n] via MFMA (M=d, N=k, K-dim=n).
// Block: 64d x 64k x 512n (nsplit=4); waves 2x2 -> each 32d x 32k.
// hi/lo bf16 LDS tiles (convert once at staging). atomicAdd epilogue.
// Grid (8, 4, 32) = 1024 blocks; LDS 40KB -> 4 blocks/CU.
// ---------------------------------------------------------------------------
__global__ __launch_bounds__(256) void k_agg(const float* __restrict__ x,
                                             const float* __restrict__ p,
                                             float* __restrict__ out) {
  const int d_base = blockIdx.x * 64;
  const int n_base = blockIdx.y * 512;
  const int b = blockIdx.z;
  const int tid = threadIdx.x;
  const int lane = tid & 63;
  const int wv = tid >> 6;
  const int wd = wv >> 1;
  const int wk = wv & 1;
  const int r = lane & 15;
  const int g = lane >> 4;

  __shared__ __align__(16) unsigned short xt[2][2][64][40];  // [buf][hi/lo][d][n]
  __shared__ __align__(16) unsigned short pt[2][2][64][40];  // [buf][hi/lo][k][n]

  const float* xb = x + (size_t)b * Dv * Nv;
  const float* pb = p + (size_t)b * Kv * Nv;

  f32x4 acc[2][2];
#pragma unroll
  for (int mb = 0; mb < 2; ++mb)
#pragma unroll
    for (int nb = 0; nb < 2; ++nb) acc[mb][nb] = (f32x4){0.f, 0.f, 0.f, 0.f};

  const int sr = tid >> 2;  // row 0..63 (d for x, k for p)
  const int sg = tid & 3;   // 8-float group

  float4 rx0, rx1, rp0, rp1;

#define GLOADA(s)                                                              \
  do {                                                                         \
    const float* sx = &xb[(size_t)(d_base + sr) * Nv + n_base + (s) * 32 + sg * 8]; \
    rx0 = *(const float4*)sx;                                                  \
    rx1 = *(const float4*)(sx + 4);                                            \
    const float* sp = &pb[(size_t)sr * Nv + n_base + (s) * 32 + sg * 8];       \
    rp0 = *(const float4*)sp;                                                  \
    rp1 = *(const float4*)(sp + 4);                                            \
  } while (0)

#define LWRITEA(buf)                                  \
  do {                                                \
    uint4 h, l;                                       \
    split8(rx0, rx1, h, l);                           \
    *(uint4*)&xt[buf][0][sr][sg * 8] = h;             \
    *(uint4*)&xt[buf][1][sr][sg * 8] = l;             \
    split8(rp0, rp1, h, l);                           \
    *(uint4*)&pt[buf][0][sr][sg * 8] = h;             \
    *(uint4*)&pt[buf][1][sr][sg * 8] = l;             \
  } while (0)

#define COMPUTEA(buf)                                                         \
  do {                                                                        \
    Frag xh[2], xl[2], ph[2], pl[2];                                          \
    _Pragma("unroll") for (int mb = 0; mb < 2; ++mb) {                        \
      xh[mb].q = *(const uint4*)&xt[buf][0][wd * 32 + mb * 16 + r][g * 8];    \
      xl[mb].q = *(const uint4*)&xt[buf][1][wd * 32 + mb * 16 + r][g * 8];    \
    }                                                                         \
    _Pragma("unroll") for (int nb = 0; nb < 2; ++nb) {                        \
      ph[nb].q = *(const uint4*)&pt[buf][0][wk * 32 + nb * 16 + r][g * 8];    \
      pl[nb].q = *(const uint4*)&pt[buf][1][wk * 32 + nb * 16 + r][g * 8];    \
    }                                                                         \
    _Pragma("unroll") for (int mb = 0; mb < 2; ++mb) {                        \
      _Pragma("unroll") for (int nb = 0; nb < 2; ++nb) {                      \
        acc[mb][nb] = __builtin_amdgcn_mfma_f32_16x16x32_bf16(xh[mb].v, ph[nb].v, acc[mb][nb], 0, 0, 0); \
        acc[mb][nb] = __builtin_amdgcn_mfma_f32_16x16x32_bf16(xh[mb].v, pl[nb].v, acc[mb][nb], 0, 0, 0); \
        acc[mb][nb] = __builtin_amdgcn_mfma_f32_16x16x32_bf16(xl[mb].v, ph[nb].v, acc[mb][nb], 0, 0, 0); \
      }                                                                       \
    }                                                                         \
  } while (0)

  GLOADA(0);
  LWRITEA(0);
  __syncthreads();
  const int STEPS = 512 / 32;  // n-range 512, 32 per step
  for (int s = 0; s < STEPS; ++s) {
    const int cur = s & 1;
    if (s + 1 < STEPS) GLOADA(s + 1);
    COMPUTEA(cur);
    if (s + 1 < STEPS) LWRITEA(cur ^ 1);
    __syncthreads();
  }
#undef GLOADA
#undef LWRITEA
#undef COMPUTEA

  // epilogue: partial-sum into out (zeroed by k_prep)
#pragma unroll
  for (int mb = 0; mb < 2; ++mb) {
#pragma unroll
    for (int nb = 0; nb < 2; ++nb) {
#pragma unroll
      for (int q = 0; q < 4; ++q) {
        const int d = d_base + wd * 32 + mb * 16 + g * 4 + q;
        const int k = wk * 32 + nb * 16 + r;
        atomicAdd(&out[((size_t)b * Dv + d) * Kv + k], acc[mb][nb][q]);
      }
    }
  }
}

// ---------------------------------------------------------------------------
// K3a: column sumsq of desc = out - centers*s_sum -> colsq atomics.
// ---------------------------------------------------------------------------
__global__ __launch_bounds__(256) void k_norm1(const float* __restrict__ out,
                                               const float* __restrict__ centers,
                                               const float* __restrict__ s_sum,
                                               float* __restrict__ colsq) {
  const int b = blockIdx.y;
  const int d0 = blockIdx.x * 64;
  const int k = threadIdx.x & 63;
  const int dq = threadIdx.x >> 6;

  __shared__ float red[4][64];

  const float sv = s_sum[b * Kv + k];
  float ssq = 0.f;
#pragma unroll
  for (int i = 0; i < 16; ++i) {
    const int d = d0 + dq * 16 + i;
    const float a = out[((size_t)b * Dv + d) * Kv + k];
    const float v = fmaf(-centers[d * Kv + k], sv, a);
    ssq = fmaf(v, v, ssq);
  }
  red[dq][k] = ssq;
  __syncthreads();
  if (threadIdx.x < 64) {
    const int kk = threadIdx.x;
    atomicAdd(&colsq[b * Kv + kk],
              red[0][kk] + red[1][kk] + red[2][kk] + red[3][kk]);
  }
}

// ---------------------------------------------------------------------------
// K3b: final scale: out = (out - centers*s_sum) * rn[k] * rtot.
// ---------------------------------------------------------------------------
__global__ __launch_bounds__(256) void k_norm2(float* __restrict__ out,
                                               const float* __restrict__ centers,
                                               const float* __restrict__ s_sum,
                                               const float* __restrict__ colsq) {
  const int b = blockIdx.y;
  const int d0 = blockIdx.x * 64;
  const int k = threadIdx.x & 63;
  const int dq = threadIdx.x >> 6;

  __shared__ float rns[64];
  __shared__ float red2[64];
  __shared__ float rtot_s;

  if (threadIdx.x < 64) {
    const float t = colsq[b * Kv + threadIdx.x];
    const float rn = 1.f / fmaxf(sqrtf(t), EPSv);
    rns[threadIdx.x] = rn;
    red2[threadIdx.x] = t * rn * rn;
  }
  __syncthreads();
  if (threadIdx.x == 0) {
    float t = 0.f;
#pragma unroll
    for (int kk = 0; kk < 64; ++kk) t += red2[kk];
    rtot_s = 1.f / fmaxf(sqrtf(t), EPSv);
  }
  __syncthreads();

  const float scale = rns[k] * rtot_s;
  const float sv = s_sum[b * Kv + k];
#pragma unroll
  for (int i = 0; i < 16; ++i) {
    const int d = d0 + dq * 16 + i;
    const size_t idx = ((size_t)b * Dv + d) * Kv + k;
    const float v = fmaf(-centers[d * Kv + k], sv, out[idx]);
    out[idx] = v * scale;
  }
}

// ---------------------------------------------------------------------------
extern "C" void kernel_launch(void* const* d_in, const int* in_sizes, int n_in,
                              void* d_out, int out_size, void* d_ws, size_t ws_size,
                              hipStream_t stream) {
  (void)in_sizes; (void)n_in; (void)out_size; (void)ws_size;
  const float* x = (const float*)d_in[0];        // [B, D, N]
  const float* W = (const float*)d_in[1];        // [K, D]
  const float* centers = (const float*)d_in[2];  // [D, K]
  float* out = (float*)d_out;                    // [B, D*K]

  // ws: p fp32 [B*K*N] (16.78MB), s_sum [B*K], colsq [B*K], Whi/Wlo bf16 [K*D]
  float* p = (float*)d_ws;
  float* s_sum = p + (size_t)Bv * Kv * Nv;
  float* colsq = s_sum + Bv * Kv;
  unsigned short* Whi = (unsigned short*)(colsq + Bv * Kv);
  unsigned short* Wlo = Whi + Kv * Dv;

  k_prep<<<dim3((Bv * Dv * Kv + 255) / 256), 256, 0, stream>>>(W, out, s_sum, Whi, Wlo);
  k_scores<<<dim3(Nv / 64, Bv), 256, 0, stream>>>(x, Whi, Wlo, p, s_sum);
  k_agg<<<dim3(Dv / 64, 4, Bv), 256, 0, stream>>>(x, p, out);
  k_norm1<<<dim3(Dv / 64, Bv), 256, 0, stream>>>(out, centers, s_sum, colsq);
  k_norm2<<<dim3(Dv / 64, Bv), 256, 0, stream>>>(out, centers, s_sum, colsq);
}